// Round 1
// baseline (206.619 us; speedup 1.0000x reference)
//
#include <hip/hip_runtime.h>
#include <hip/hip_bf16.h>
#include <stdint.h>

// SelfAttention1D: B=8,T=2048,D_IN=512,D_ATTN=8,D_OUT=512, scores = (QK^T)^8, softmax, @V
// 4 kernels: W_v transpose/cvt -> Q,K high-precision -> V bf16 MFMA GEMM (pre-swizzled V^T
// layout) -> flash attention with exact-precomputed row max.
// Workspace: WvT 512KB @0, Q 512KB @512K, K 512KB @1M, Vg 16MB @1.5M  (~17.6MB total)

typedef float f32x4_t __attribute__((ext_vector_type(4)));
typedef short s16x8_t __attribute__((ext_vector_type(8)));
typedef unsigned int u32;

static __device__ __forceinline__ unsigned short f2bf(float x){
  union { float f; u32 u; } v; v.f = x;
  return (unsigned short)((v.u + 0x7FFFu + ((v.u >> 16) & 1u)) >> 16);
}

static __device__ __forceinline__ void gload16(const void* g, void* l){
  __builtin_amdgcn_global_load_lds((const __attribute__((address_space(1))) u32*)g,
                                   (__attribute__((address_space(3))) u32*)l, 16, 0, 0);
}

static __device__ __forceinline__ float dot8(const float* q, const float4& a, const float4& b){
  float s = q[0] * a.x;
  s = fmaf(q[1], a.y, s); s = fmaf(q[2], a.z, s); s = fmaf(q[3], a.w, s);
  s = fmaf(q[4], b.x, s); s = fmaf(q[5], b.y, s); s = fmaf(q[6], b.z, s);
  s = fmaf(q[7], b.w, s);
  return s;
}

// ---------------- K0: W_v [512][512] f32 -> WvT [c][d] bf16 ----------------
__global__ __launch_bounds__(256) void k_wvT(const float* __restrict__ Wv,
                                             unsigned short* __restrict__ WvT){
  __shared__ __align__(16) float tile[64][68];
  const int t = threadIdx.x;
  const int dbase = (blockIdx.x >> 3) * 64;
  const int cbase = (blockIdx.x & 7) * 64;
  {
    const int dl = t >> 2, cq = (t & 3) * 16;
    const float* src = Wv + (size_t)(dbase + dl) * 512 + cbase + cq;
#pragma unroll
    for (int i = 0; i < 16; i += 4){
      float4 v = *(const float4*)(src + i);
      tile[dl][cq + i + 0] = v.x; tile[dl][cq + i + 1] = v.y;
      tile[dl][cq + i + 2] = v.z; tile[dl][cq + i + 3] = v.w;
    }
  }
  __syncthreads();
  const int cl = t >> 2, dq = (t & 3) * 16;
  __align__(16) unsigned short o[16];
#pragma unroll
  for (int i = 0; i < 16; ++i) o[i] = f2bf(tile[dq + i][cl]);
  unsigned short* dst = WvT + (size_t)(cbase + cl) * 512 + dbase + dq;
  *(uint4*)dst = *(const uint4*)o;
  *(uint4*)(dst + 8) = *(const uint4*)(o + 8);
}

// ---------------- K1: Q,K fp32 (blocked-fp64 accumulation) ----------------
// 16 tokens/block, thread = (token, f) with f in 0..15 (0-7 -> Q, 8-15 -> K)
__global__ __launch_bounds__(256) void k_qk(const float* __restrict__ In,
                                            const float* __restrict__ Wq,
                                            const float* __restrict__ Wk,
                                            float* __restrict__ Qo,
                                            float* __restrict__ Ko){
  __shared__ __align__(16) float wt[16 * 512];
  const int t = threadIdx.x;
#pragma unroll
  for (int i = 0; i < 16; i += 4){
    float4 vq = *(const float4*)(Wq + t * 16 + i);
    float4 vk = *(const float4*)(Wk + t * 16 + i);
    const float* pq = &vq.x;
    const float* pk = &vk.x;
#pragma unroll
    for (int j = 0; j < 4; ++j){
      int flat = t * 16 + i + j;
      int d = flat >> 3, f = flat & 7;
      wt[f * 512 + ((((d >> 2) ^ f) << 2) | (d & 3))] = pq[j];
      int fk = f + 8;
      wt[fk * 512 + ((((d >> 2) ^ (fk & 7)) << 2) | (d & 3))] = pk[j];
    }
  }
  __syncthreads();
  const int tok = blockIdx.x * 16 + (t >> 4);
  const int f = t & 15;
  const float* inrow = In + (size_t)tok * 512;
  const float* wrow = &wt[f * 512];
  const int swz = f & 7;
  double acc = 0.0;
  for (int cb = 0; cb < 128; cb += 8){
    float part = 0.f;
#pragma unroll
    for (int c = cb; c < cb + 8; ++c){
      float4 x = *(const float4*)(inrow + c * 4);
      float4 ww = *(const float4*)(wrow + ((c ^ swz) << 2));
      part = fmaf(x.x, ww.x, part); part = fmaf(x.y, ww.y, part);
      part = fmaf(x.z, ww.z, part); part = fmaf(x.w, ww.w, part);
    }
    acc += (double)part;
  }
  float r = (float)acc;
  if (f < 8) Qo[(size_t)tok * 8 + f] = r;
  else       Ko[(size_t)tok * 8 + (f - 8)] = r;
}

// ---------------- K2: V = In @ Wv, bf16 MFMA, output in swizzled V^T layout ----------
// Vg element addr (shorts): b*1048576 + (s>>5)*16384 + c*32 + (((s>>3)&3)^((c>>1)&3))*8 + (s&7)
__global__ __launch_bounds__(256) void k_vproj(const float* __restrict__ In,
                                               const unsigned short* __restrict__ WvT,
                                               unsigned short* __restrict__ Vg){
  __shared__ __align__(16) char smem[65536];
  char* Ab = smem;           // [2][8192] bf16 A tile 128x32, swizzled
  char* Bb = smem + 16384;   // [2][8192] bf16 B tile (WvT) 128x32, swizzled
  char* Img = smem + 32768;  // [32768] epilogue image
  const int t = threadIdx.x;
  const int w = t >> 6, lane = t & 63;
  const int mt = blockIdx.x >> 2, nt = blockIdx.x & 3;
  const int wm = w >> 1, wn = w & 1;
  const int asub = lane & 3;
  int arow[2], acr[2];
#pragma unroll
  for (int i = 0; i < 2; ++i){
    arow[i] = (w * 2 + i) * 16 + (lane >> 2);
    acr[i]  = asub ^ ((arow[i] >> 1) & 3);
  }
  f32x4_t acc[4][4];
#pragma unroll
  for (int m = 0; m < 4; ++m)
#pragma unroll
    for (int n = 0; n < 4; ++n)
      acc[m][n] = (f32x4_t){0.f, 0.f, 0.f, 0.f};

  auto stageB = [&](int kk, int sel){
#pragma unroll
    for (int i = 0; i < 2; ++i){
      int id = w * 2 + i;
      const unsigned short* gb = WvT + (size_t)(nt * 128 + arow[i]) * 512 + kk * 32 + acr[i] * 8;
      gload16(gb, Bb + sel * 8192 + id * 1024);
    }
  };
  auto loadA = [&](int kk, float4* x, float4* y){
#pragma unroll
    for (int i = 0; i < 2; ++i){
      const float* ga = In + (size_t)(mt * 128 + arow[i]) * 512 + kk * 32 + acr[i] * 8;
      x[i] = *(const float4*)ga;
      y[i] = *(const float4*)(ga + 4);
    }
  };
  auto writeA = [&](const float4* x, const float4* y, int sel){
#pragma unroll
    for (int i = 0; i < 2; ++i){
      __align__(16) unsigned short pk[8] = {
        f2bf(x[i].x), f2bf(x[i].y), f2bf(x[i].z), f2bf(x[i].w),
        f2bf(y[i].x), f2bf(y[i].y), f2bf(y[i].z), f2bf(y[i].w)};
      *(uint4*)(Ab + sel * 8192 + arow[i] * 64 + asub * 16) = *(const uint4*)pk;
    }
  };
  {
    float4 x[2], y[2];
    loadA(0, x, y);
    stageB(0, 0);
    writeA(x, y, 0);
    __syncthreads();
  }
  for (int kk = 0; kk < 16; ++kk){
    const int cur = kk & 1;
    float4 x[2], y[2];
    if (kk < 15){
      loadA(kk + 1, x, y);        // issue early, consume after MFMA (hide latency)
      stageB(kk + 1, cur ^ 1);
    }
    s16x8_t a[4], bf[4];
#pragma unroll
    for (int m = 0; m < 4; ++m){
      int row = wm * 64 + m * 16 + (lane & 15);
      int chn = (lane >> 4) ^ ((row >> 1) & 3);
      a[m] = *(const s16x8_t*)(Ab + cur * 8192 + row * 64 + chn * 16);
    }
#pragma unroll
    for (int n = 0; n < 4; ++n){
      int col = wn * 64 + n * 16 + (lane & 15);
      int chn = (lane >> 4) ^ ((col >> 1) & 3);
      bf[n] = *(const s16x8_t*)(Bb + cur * 8192 + col * 64 + chn * 16);
    }
#pragma unroll
    for (int m = 0; m < 4; ++m)
#pragma unroll
      for (int n = 0; n < 4; ++n)
        acc[m][n] = __builtin_amdgcn_mfma_f32_16x16x32_bf16(a[m], bf[n], acc[m][n], 0, 0, 0);
    if (kk < 15) writeA(x, y, cur ^ 1);
    __syncthreads();
  }
  // epilogue: build V_g image in LDS, then coalesced linear copy
#pragma unroll
  for (int m = 0; m < 4; ++m){
    int tl = wm * 64 + m * 16 + ((lane >> 4) << 2);
    int sg = tl >> 5;
    int sin = tl & 31;
#pragma unroll
    for (int n = 0; n < 4; ++n){
      int cl = wn * 64 + n * 16 + (lane & 15);
      __align__(8) unsigned short pk2[4];
#pragma unroll
      for (int j = 0; j < 4; ++j) pk2[j] = f2bf(acc[m][n][j]);
      int boff = sg * 8192 + cl * 64 + ((((sin >> 3) & 3) ^ ((cl >> 1) & 3)) << 4) + (sin & 7) * 2;
      *(uint2*)(Img + boff) = *(const uint2*)pk2;
    }
  }
  __syncthreads();
  const size_t bbE = (size_t)(mt >> 4) * 1048576;
  const int tile0 = (mt & 15) * 4;
#pragma unroll
  for (int i = 0; i < 8; ++i){
    int o = (i * 256 + t) * 16;
    int sg = o >> 13, rem = o & 8191;
    unsigned short* dst = Vg + bbE + (size_t)(tile0 + sg) * 16384 + nt * 4096 + (rem >> 1);
    *(uint4*)dst = *(const uint4*)(Img + o);
  }
}

// ---------------- K3: flash attention with exact precomputed row max ----------------
// grid 256: b = bid&7 (XCD pin), qt = (bid>>3)>>1 (128 rows), ch = (bid>>3)&1 (256 cols)
__global__ __launch_bounds__(512) void k_attn(const float* __restrict__ Qg,
                                              const float* __restrict__ Kg,
                                              const unsigned short* __restrict__ Vg,
                                              float* __restrict__ Out){
  __shared__ __align__(16) char smem[65536];
  // main: VBUF 2x16384 @0 ; PBUF 2x8192 @32768 ; RED @49152 ; epilogue reuses all
  const int t = threadIdx.x;
  const int w = t >> 6, lane = t & 63;
  const int h = w >> 2, g = w & 3;
  const int b = blockIdx.x & 7;
  const int rr = blockIdx.x >> 3;
  const int qt = rr >> 1, ch = rr & 1;
  const int qbase = qt * 128;
  const int q_l = h * 64 + lane;

  float qreg[8];
  {
    const float* Qp = Qg + (size_t)(b * 2048 + qbase + q_l) * 8;
    float4 a = *(const float4*)Qp;
    float4 c = *(const float4*)(Qp + 4);
    qreg[0] = a.x; qreg[1] = a.y; qreg[2] = a.z; qreg[3] = a.w;
    qreg[4] = c.x; qreg[5] = c.y; qreg[6] = c.z; qreg[7] = c.w;
  }
  const float* Kp = Kg + (size_t)b * (2048 * 8);
  const unsigned short* Vbase = Vg + (size_t)b * 1048576 + ch * 8192;

  auto stageV = [&](int tt, int sel){
#pragma unroll
    for (int i = 0; i < 2; ++i){
      int id = w * 2 + i;
      gload16(Vbase + (size_t)tt * 16384 + id * 512 + lane * 8,
              smem + sel * 16384 + id * 1024);
    }
  };

  stageV(0, 0);

  float* red = (float*)(smem + 49152);
  float* fin = (float*)(smem + 49152 + 2048);

  // prepass: exact row max of p = s^8 over all 2048 keys (wave g covers keys == [8g,8g+8) mod 32)
  {
    float ml = 0.f;
    for (int it = 0; it < 64; ++it){
      const float* kb = Kp + (size_t)(it * 32 + g * 8) * 8;
#pragma unroll
      for (int j = 0; j < 8; ++j){
        float4 k0 = *(const float4*)(kb + j * 8);
        float4 k1 = *(const float4*)(kb + j * 8 + 4);
        float s = dot8(qreg, k0, k1);
        float s2 = s * s; float s4 = s2 * s2; float p = s4 * s4;
        ml = fmaxf(ml, p);
      }
    }
    red[q_l * 4 + g] = ml;
  }
  __syncthreads();
  if (t < 128) fin[t] = fmaxf(fmaxf(red[t * 4], red[t * 4 + 1]),
                              fmaxf(red[t * 4 + 2], red[t * 4 + 3]));
  __syncthreads();
  const float mreg = fin[q_l];
  float lpart = 0.f;

  auto scoreTile = [&](int tt, int sel){
    const float* kb = Kp + (size_t)(tt * 32 + g * 8) * 8;
    __align__(16) unsigned short pk[8];
#pragma unroll
    for (int j = 0; j < 8; ++j){
      float4 k0 = *(const float4*)(kb + j * 8);
      float4 k1 = *(const float4*)(kb + j * 8 + 4);
      float s = dot8(qreg, k0, k1);
      float s2 = s * s; float s4 = s2 * s2; float p = s4 * s4;
      float e = __expf(p - mreg);
      lpart += e;
      pk[j] = f2bf(e);
    }
    *(uint4*)(smem + 32768 + sel * 8192 + q_l * 64 + ((g ^ ((q_l >> 1) & 3)) << 4)) = *(const uint4*)pk;
  };

  scoreTile(0, 0);
  __syncthreads();

  f32x4_t acc[4][4];
#pragma unroll
  for (int m = 0; m < 4; ++m)
#pragma unroll
    for (int n = 0; n < 4; ++n)
      acc[m][n] = (f32x4_t){0.f, 0.f, 0.f, 0.f};

  for (int tt = 0; tt < 64; ++tt){
    const int cur = tt & 1;
    if (tt < 63) stageV(tt + 1, cur ^ 1);
    s16x8_t a[4];
#pragma unroll
    for (int m = 0; m < 4; ++m){
      int row = h * 64 + m * 16 + (lane & 15);
      int chn = (lane >> 4) ^ ((row >> 1) & 3);
      a[m] = *(const s16x8_t*)(smem + 32768 + cur * 8192 + row * 64 + chn * 16);
    }
#pragma unroll
    for (int n = 0; n < 4; ++n){
      int col = g * 64 + n * 16 + (lane & 15);
      int chn = (lane >> 4) ^ ((col >> 1) & 3);
      s16x8_t bfr = *(const s16x8_t*)(smem + cur * 16384 + col * 64 + chn * 16);
#pragma unroll
      for (int m = 0; m < 4; ++m)
        acc[m][n] = __builtin_amdgcn_mfma_f32_16x16x32_bf16(a[m], bfr, acc[m][n], 0, 0, 0);
    }
    if (tt < 63) scoreTile(tt + 1, cur ^ 1);
    __syncthreads();
  }

  // softmax denominator
  red[q_l * 4 + g] = lpart;
  __syncthreads();
  if (t < 128) fin[t] = red[t * 4] + red[t * 4 + 1] + red[t * 4 + 2] + red[t * 4 + 3];
  __syncthreads();
  float linv[4][4];
#pragma unroll
  for (int m = 0; m < 4; ++m)
#pragma unroll
    for (int j = 0; j < 4; ++j)
      linv[m][j] = 1.f / fin[h * 64 + m * 16 + ((lane >> 4) << 2) + j];
  __syncthreads();

  // epilogue: normalize, LDS-transpose, coalesced stores (2 rounds of 64KB)
#pragma unroll
  for (int mq = 0; mq < 2; ++mq){
#pragma unroll
    for (int mr = 0; mr < 2; ++mr){
      const int m = mq * 2 + mr;
#pragma unroll
      for (int n = 0; n < 4; ++n){
        int cl = g * 64 + n * 16 + (lane & 15);
#pragma unroll
        for (int j = 0; j < 4; ++j){
          int qimg = mr * 16 + ((lane >> 4) << 2) + j;
          *(float*)(smem + h * 32768 + qimg * 1024 + cl * 4) = acc[m][n][j] * linv[m][j];
        }
      }
    }
    __syncthreads();
#pragma unroll
    for (int i = 0; i < 8; ++i){
      int o = (i * 512 + t) * 16;
      int h2 = o >> 15, rem = o & 32767;
      int qimg = rem >> 10, cfl = (rem & 1023) >> 2;
      int qg2 = qbase + h2 * 64 + mq * 32 + qimg;
      float* dst = Out + (size_t)(b * 2048 + qg2) * 512 + ch * 256 + cfl;
      *(float4*)dst = *(const float4*)(smem + o);
    }
    __syncthreads();
  }
}

extern "C" void kernel_launch(void* const* d_in, const int* in_sizes, int n_in,
                              void* d_out, int out_size, void* d_ws, size_t ws_size,
                              hipStream_t stream){
  const float* In = (const float*)d_in[0];
  const float* Wq = (const float*)d_in[1];
  const float* Wk = (const float*)d_in[2];
  const float* Wv = (const float*)d_in[3];
  // power (d_in[4]) is the constant 8; hardcoded as three squarings.
  char* ws = (char*)d_ws;
  unsigned short* WvT = (unsigned short*)(ws);
  float* Q            = (float*)(ws + 524288);
  float* K            = (float*)(ws + 1048576);
  unsigned short* Vg  = (unsigned short*)(ws + 1572864);   // 16MB; total ws use ~17.6MB
  float* Out = (float*)d_out;

  hipLaunchKernelGGL(k_wvT,   dim3(64),   dim3(256), 0, stream, Wv, WvT);
  hipLaunchKernelGGL(k_qk,    dim3(1024), dim3(256), 0, stream, In, Wq, Wk, Q, K);
  hipLaunchKernelGGL(k_vproj, dim3(512),  dim3(256), 0, stream, In, WvT, Vg);
  hipLaunchKernelGGL(k_attn,  dim3(256),  dim3(512), 0, stream, Q, K, Vg, Out);
}